// Round 5
// baseline (172.250 us; speedup 1.0000x reference)
//
#include <hip/hip_runtime.h>

// ActivationDelta: out = where(ACT_MASK[col] & (v != 0), clamp(v + delta, 0, 1), v)
// ACT columns (FEAT_DIM=2133): {0, 81, 165+3j : j in [0,40)}  (42 columns)
// Memory-bound streaming: 426.6 MB in + 426.6 MB out (irreducible).
// R5: ONE structural change vs R4 — per-block CONTIGUOUS segments (balanced
//     tile split) so each block's R/W streams advance sequentially through
//     DRAM instead of jumping 32 MB per iteration (row-buffer locality,
//     fewer stream relocations). Plus nt on loads as well as stores
//     (read-once / write-once data; keep L2 out of the way).

#define FEAT_DIM 2133u
#define TILE_F4  1024u   // float4s per tile = 16 KB

typedef float f32x4 __attribute__((ext_vector_type(4)));

__device__ __forceinline__ bool is_act_col(unsigned c) {
    // unsigned wrap: c < 165 -> (c-165) huge -> range check fails
    unsigned d = c - 165u;
    return (c == 0u) | (c == 81u) | ((d <= 117u) & (d % 3u == 0u));
}

__device__ __forceinline__ f32x4 proc4(f32x4 v, unsigned i /*float4 index*/, float dlt) {
    unsigned c0 = (i * 4u) % FEAT_DIM;
    f32x4 r;
#pragma unroll
    for (int k = 0; k < 4; ++k) {
        unsigned c = c0 + (unsigned)k;
        c = (c >= FEAT_DIM) ? (c - FEAT_DIM) : c;
        float x = v[k];
        float b = fminf(fmaxf(x + dlt, 0.0f), 1.0f);
        bool ap = is_act_col(c) & (x != 0.0f);
        r[k] = ap ? b : x;
    }
    return r;
}

__global__ void __launch_bounds__(256)
ActivationDelta_19318762897441_kernel(const float* __restrict__ in,
                                      const float* __restrict__ dptr,
                                      float* __restrict__ out,
                                      unsigned n4, unsigned ntiles, unsigned n)
{
    const float dlt = dptr[0];
    const unsigned t = threadIdx.x;

    const f32x4* __restrict__ in4 = reinterpret_cast<const f32x4*>(in);
    f32x4* __restrict__ out4      = reinterpret_cast<f32x4*>(out);

    // Balanced contiguous split of ntiles across gridDim.x blocks:
    // first r blocks get q+1 tiles, rest get q.
    const unsigned q = ntiles / gridDim.x;
    const unsigned r = ntiles % gridDim.x;
    const unsigned b = blockIdx.x;
    const unsigned t0 = b * q + (b < r ? b : r);
    const unsigned t1 = t0 + q + (b < r ? 1u : 0u);

    for (unsigned tile = t0; tile < t1; ++tile) {
        unsigned base = tile * TILE_F4 + t;
        f32x4 v0 = __builtin_nontemporal_load(&in4[base]);
        f32x4 v1 = __builtin_nontemporal_load(&in4[base + 256u]);
        f32x4 v2 = __builtin_nontemporal_load(&in4[base + 512u]);
        f32x4 v3 = __builtin_nontemporal_load(&in4[base + 768u]);

        v0 = proc4(v0, base,        dlt);
        v1 = proc4(v1, base + 256u, dlt);
        v2 = proc4(v2, base + 512u, dlt);
        v3 = proc4(v3, base + 768u, dlt);

        __builtin_nontemporal_store(v0, &out4[base]);
        __builtin_nontemporal_store(v1, &out4[base + 256u]);
        __builtin_nontemporal_store(v2, &out4[base + 512u]);
        __builtin_nontemporal_store(v3, &out4[base + 768u]);
    }

    // float4 tail after the last full tile (grid-stride)
    for (unsigned i = ntiles * TILE_F4 + blockIdx.x * 256u + t; i < n4;
         i += gridDim.x * 256u) {
        f32x4 v = __builtin_nontemporal_load(&in4[i]);
        v = proc4(v, i, dlt);
        __builtin_nontemporal_store(v, &out4[i]);
    }

    // scalar tail (n % 4; n = 50000*2133 is divisible by 4, but be safe)
    for (unsigned j = n4 * 4u + blockIdx.x * 256u + t; j < n;
         j += gridDim.x * 256u) {
        unsigned c = j % FEAT_DIM;
        float x = in[j];
        float bm = fminf(fmaxf(x + dlt, 0.0f), 1.0f);
        bool ap = is_act_col(c) & (x != 0.0f);
        out[j] = ap ? bm : x;
    }
}

extern "C" void kernel_launch(void* const* d_in, const int* in_sizes, int n_in,
                              void* d_out, int out_size, void* d_ws, size_t ws_size,
                              hipStream_t stream) {
    const float* in  = (const float*)d_in[0];
    const float* dlt = (const float*)d_in[1];
    float* out       = (float*)d_out;

    const unsigned n      = (unsigned)in_sizes[0];
    const unsigned n4     = n / 4u;
    const unsigned ntiles = n4 / TILE_F4;

    const int block = 256;
    unsigned want = ntiles ? ntiles : 1u;
    unsigned grid = want < 2048u ? want : 2048u;

    ActivationDelta_19318762897441_kernel<<<dim3(grid), dim3(block), 0, stream>>>(
        in, dlt, out, n4, ntiles, n);
}

// Round 6
// 140.782 us; speedup vs baseline: 1.2235x; 1.2235x over previous
//
#include <hip/hip_runtime.h>

// ActivationDelta: out = where(ACT_MASK[col] & (v != 0), clamp(v + delta, 0, 1), v)
// ACT columns (FEAT_DIM=2133): {0, 81, 165+3j : j in [0,40)}  (42 columns)
// Memory-bound streaming: 426.6 MB in + 426.6 MB out (irreducible).
// R6: ONE change vs R4 — monolithic launch, ONE float4 per thread, no loop
//     (canonical copy-ubench / fill-kernel structure). Blocks retire and the
//     CP streams new ones in dispatch order -> strictly advancing DRAM window.
//     nt-store kept (R4's small win), cached loads kept.

#define FEAT_DIM 2133u

typedef float f32x4 __attribute__((ext_vector_type(4)));

__device__ __forceinline__ bool is_act_col(unsigned c) {
    // unsigned wrap: c < 165 -> (c-165) huge -> range check fails
    unsigned d = c - 165u;
    return (c == 0u) | (c == 81u) | ((d <= 117u) & (d % 3u == 0u));
}

__global__ void __launch_bounds__(256)
ActivationDelta_19318762897441_kernel(const float* __restrict__ in,
                                      const float* __restrict__ dptr,
                                      float* __restrict__ out,
                                      unsigned n4)
{
    const unsigned i = blockIdx.x * 256u + threadIdx.x;
    if (i >= n4) return;

    const float dlt = dptr[0];
    const f32x4* __restrict__ in4 = reinterpret_cast<const f32x4*>(in);
    f32x4* __restrict__ out4      = reinterpret_cast<f32x4*>(out);

    f32x4 v = in4[i];
    unsigned c0 = (i * 4u) % FEAT_DIM;
    f32x4 r;
#pragma unroll
    for (int k = 0; k < 4; ++k) {
        unsigned c = c0 + (unsigned)k;
        c = (c >= FEAT_DIM) ? (c - FEAT_DIM) : c;
        float x = v[k];
        float b = fminf(fmaxf(x + dlt, 0.0f), 1.0f);
        bool ap = is_act_col(c) & (x != 0.0f);
        r[k] = ap ? b : x;
    }
    __builtin_nontemporal_store(r, &out4[i]);
}

// scalar tail kernel (n % 4 elements; n = 50000*2133 is divisible by 4,
// but keep correctness for generality)
__global__ void __launch_bounds__(256)
ActivationDelta_tail_kernel(const float* __restrict__ in,
                            const float* __restrict__ dptr,
                            float* __restrict__ out,
                            unsigned start, unsigned n)
{
    unsigned j = start + blockIdx.x * 256u + threadIdx.x;
    if (j >= n) return;
    const float dlt = dptr[0];
    unsigned c = j % FEAT_DIM;
    float x = in[j];
    float b = fminf(fmaxf(x + dlt, 0.0f), 1.0f);
    bool ap = is_act_col(c) & (x != 0.0f);
    out[j] = ap ? b : x;
}

extern "C" void kernel_launch(void* const* d_in, const int* in_sizes, int n_in,
                              void* d_out, int out_size, void* d_ws, size_t ws_size,
                              hipStream_t stream) {
    const float* in  = (const float*)d_in[0];
    const float* dlt = (const float*)d_in[1];
    float* out       = (float*)d_out;

    const unsigned n  = (unsigned)in_sizes[0];
    const unsigned n4 = n / 4u;

    const unsigned grid = (n4 + 255u) / 256u;
    ActivationDelta_19318762897441_kernel<<<dim3(grid), dim3(256), 0, stream>>>(
        in, dlt, out, n4);

    const unsigned tail = n - n4 * 4u;
    if (tail) {
        const unsigned tgrid = (tail + 255u) / 256u;
        ActivationDelta_tail_kernel<<<dim3(tgrid), dim3(256), 0, stream>>>(
            in, dlt, out, n4 * 4u, n);
    }
}